// Round 14
// baseline (239.776 us; speedup 1.0000x reference)
//
#include <hip/hip_runtime.h>
#include <hip/hip_bf16.h>
#include <cmath>

// Problem constants
#define BB 2
#define TT 2048
#define CC 1024
#define HH 16
#define DD 64
#define ROWS (BB*TT)          // 4096
#define N1 (3*CC)             // 3072
#define EPS 1e-6f

using short8 = __attribute__((ext_vector_type(8))) short;
using f32x4  = __attribute__((ext_vector_type(4))) float;

__device__ __forceinline__ void gl_lds16(const __hip_bfloat16* g, unsigned short* l) {
    __builtin_amdgcn_global_load_lds(
        (const __attribute__((address_space(1))) unsigned int*)(g),
        (__attribute__((address_space(3))) unsigned int*)(l), 16, 0, 0);
}

__device__ __forceinline__ unsigned int bf16pair(float a, float b) {
    __hip_bfloat16 ha = (__hip_bfloat16)a, hb = (__hip_bfloat16)b;  // RNE
    unsigned short ua = *(unsigned short*)&ha, ub = *(unsigned short*)&hb;
    return (unsigned int)ua | ((unsigned int)ub << 16);
}

__device__ __forceinline__ float bf2f(unsigned short u) {
    unsigned int v = (unsigned int)u << 16;
    return *(float*)&v;
}

// ---- prep: blk 0..63 weight column-strips (block-local colsq, no atomics);
//      blk 64..4159 rowsq+cast (+osq zero); blk 4160..4415 rope table.
__global__ void prep_all2(const float* __restrict__ X, float* __restrict__ xsq,
                          __hip_bfloat16* __restrict__ Xb, float* __restrict__ osq,
                          float* __restrict__ rope,
                          const float* __restrict__ Wa, __hip_bfloat16* __restrict__ WaT,
                          float* __restrict__ wsqa,
                          const float* __restrict__ Wp, __hip_bfloat16* __restrict__ WpT,
                          float* __restrict__ wsqp) {
    int blk = blockIdx.x;
    int t = threadIdx.x;
    if (blk < 64) {
        // one block owns a 64-wide column strip over all K=1024
        const float* W; __hip_bfloat16* Wt; float* wsq; int N, n0;
        if (blk < 48) { W = Wa; Wt = WaT; wsq = wsqa; N = N1; n0 = blk * 64; }
        else          { W = Wp; Wt = WpT; wsq = wsqp; N = CC; n0 = (blk - 48) * 64; }
        __shared__ unsigned short tile[64][65];
        __shared__ float sred[4][64];
        int c = t & 63, rg = t >> 6;
        float part = 0.f;
        for (int kt = 0; kt < 16; ++kt) {
            int k0 = kt * 64;
            __syncthreads();           // protect tile across iterations
#pragma unroll
            for (int rr = 0; rr < 16; ++rr) {
                int r = rg + rr * 4;
                float f = W[(size_t)(k0 + r) * N + n0 + c];
                __hip_bfloat16 hh = (__hip_bfloat16)f;
                tile[r][c] = *(unsigned short*)&hh;
                part += f * f;
            }
            __syncthreads();
#pragma unroll
            for (int rr = 0; rr < 16; ++rr) {
                int r = rg + rr * 4;
                unsigned short u = tile[c][r];
                Wt[(size_t)(n0 + r) * CC + k0 + c] = *(__hip_bfloat16*)&u;
            }
        }
        sred[rg][c] = part;
        __syncthreads();
        if (rg == 0) wsq[n0 + c] = sred[0][c] + sred[1][c] + sred[2][c] + sred[3][c];
        return;
    }
    if (blk < 64 + ROWS) {
        int row = blk - 64;
        const float* xr = X + (size_t)row * CC + t * 4;
        float4 v = *(const float4*)xr;
        float p = v.x * v.x + v.y * v.y + v.z * v.z + v.w * v.w;
        uint2 w;
        w.x = bf16pair(v.x, v.y);
        w.y = bf16pair(v.z, v.w);
        *(uint2*)((unsigned short*)Xb + (size_t)row * CC + t * 4) = w;
#pragma unroll
        for (int off = 32; off > 0; off >>= 1) p += __shfl_xor(p, off, 64);
        __shared__ float s4[4];
        if ((t & 63) == 0) s4[t >> 6] = p;
        __syncthreads();
        if (t == 0) { xsq[row] = s4[0] + s4[1] + s4[2] + s4[3]; osq[row] = 0.f; }
        return;
    }
    int idx = (blk - 64 - ROWS) * 256 + t;     // 0..65535
    int tt = idx >> 5, i = idx & 31;
    double freq = pow(10000.0, -(double)i / 32.0);
    float ang = (float)tt * (float)freq;
    rope[idx * 2 + 0] = cosf(ang);
    rope[idx * 2 + 1] = sinf(ang);
}

// --------- gemm1: x @ w_attn, yat epilogue; Q/K -> [bh][t][d], V -> Vtb [bh][d][t]
// 128x128 tile, BK=64. NO rope (K roped by ropek, Q roped in attention).
__global__ __launch_bounds__(256) void yat_gemm_qkv3(
    const __hip_bfloat16* __restrict__ A,
    const __hip_bfloat16* __restrict__ Bt,
    const float* __restrict__ xsq, const float* __restrict__ wsq,
    const float* __restrict__ bias,
    __hip_bfloat16* __restrict__ Qb, __hip_bfloat16* __restrict__ Kb,
    __hip_bfloat16* __restrict__ Vtb, float scale) {
    const int K = CC;
    __shared__ __align__(16) unsigned short As0[128 * 32], As1[128 * 32];
    __shared__ __align__(16) unsigned short Bs0[128 * 32], Bs1[128 * 32];
    int tid = threadIdx.x;
    int wave = tid >> 6, lane = tid & 63, quad = lane >> 4, l16 = lane & 15;
    int wr = wave >> 1, wc = wave & 1;
    int m0 = blockIdx.y * 128, n0 = blockIdx.x * 128;

    f32x4 acc[4][4];
#pragma unroll
    for (int mt = 0; mt < 4; ++mt)
#pragma unroll
        for (int nt = 0; nt < 4; ++nt) acc[mt][nt] = f32x4{0.f, 0.f, 0.f, 0.f};

    int srow = lane >> 2, soff = (lane & 3) << 3;
    for (int k0 = 0; k0 < K; k0 += 64) {
        __syncthreads();
#pragma unroll
        for (int i = 0; i < 2; ++i) {
            int rowc = (wave * 2 + i) * 16;
            const __hip_bfloat16* ap = A + (size_t)(m0 + rowc + srow) * K + k0 + soff;
            gl_lds16(ap,      As0 + rowc * 32);
            gl_lds16(ap + 32, As1 + rowc * 32);
            const __hip_bfloat16* bp = Bt + (size_t)(n0 + rowc + srow) * K + k0 + soff;
            gl_lds16(bp,      Bs0 + rowc * 32);
            gl_lds16(bp + 32, Bs1 + rowc * 32);
        }
        __syncthreads();
#pragma unroll
        for (int h = 0; h < 2; ++h) {
            const unsigned short* Ah = h ? As1 : As0;
            const unsigned short* Bh = h ? Bs1 : Bs0;
            short8 af[4], bf[4];
#pragma unroll
            for (int mt = 0; mt < 4; ++mt)
                af[mt] = *(const short8*)(Ah + (wr * 64 + mt * 16 + l16) * 32 + quad * 8);
#pragma unroll
            for (int nt = 0; nt < 4; ++nt)
                bf[nt] = *(const short8*)(Bh + (wc * 64 + nt * 16 + l16) * 32 + quad * 8);
#pragma unroll
            for (int mt = 0; mt < 4; ++mt)
#pragma unroll
                for (int nt = 0; nt < 4; ++nt)
                    acc[mt][nt] = __builtin_amdgcn_mfma_f32_16x16x32_bf16(af[mt], bf[nt], acc[mt][nt], 0, 0, 0);
        }
    }
    int mb = m0 + wr * 64 + quad * 4;
    int sec = n0 >> 10;             // 0=Q 1=K 2=V (uniform per block: 128 | 1024)
    if (sec == 2) {
#pragma unroll
        for (int nt = 0; nt < 4; ++nt) {
            int col = n0 + wc * 64 + nt * 16 + l16;
            float wq = wsq[col], bs = bias[col];
            int cc2 = col & 1023, h = cc2 >> 6, d = cc2 & 63;
#pragma unroll
            for (int mt = 0; mt < 4; ++mt) {
                int rowb = mb + mt * 16;
                int bI = rowb >> 11, tb2 = rowb & (TT - 1);
                float y[4];
#pragma unroll
                for (int r = 0; r < 4; ++r) {
                    float dot = acc[mt][nt][r];
                    float dist = xsq[rowb + r] + wq - 2.f * dot + EPS;
                    y[r] = dot * dot / dist * scale + bs;
                }
                uint2 w2;
                w2.x = bf16pair(y[0], y[1]);
                w2.y = bf16pair(y[2], y[3]);
                *(uint2*)((unsigned short*)Vtb + (((size_t)bI * HH + h) * DD + d) * TT + tb2) = w2;
            }
        }
    } else {
        __hip_bfloat16* dst = sec ? Kb : Qb;
#pragma unroll
        for (int nt = 0; nt < 4; ++nt) {
            int col = n0 + wc * 64 + nt * 16 + l16;
            float wq = wsq[col], bs = bias[col];
            int cc2 = col & 1023, h = cc2 >> 6, d = cc2 & 63;
#pragma unroll
            for (int mt = 0; mt < 4; ++mt) {
#pragma unroll
                for (int r = 0; r < 4; ++r) {
                    int row = mb + mt * 16 + r;
                    float dot = acc[mt][nt][r];
                    float dist = xsq[row] + wq - 2.f * dot + EPS;
                    float yv = dot * dot / dist * scale + bs;
                    int t2 = row & (TT - 1), bI = row >> 11;
                    dst[(((size_t)bI * HH + h) * TT + t2) * DD + d] = (__hip_bfloat16)yv;
                }
            }
        }
    }
}

// ------------- rope K in place (pure elementwise, one 16-short chunk/thread)
__global__ __launch_bounds__(256) void ropek(
    unsigned short* __restrict__ Kb, const float* __restrict__ rope) {
    int u = blockIdx.x * 256 + threadIdx.x;    // 0..262143
    int bh = u >> 13, r2 = u & 8191, t = r2 >> 2, g = r2 & 3;
    unsigned short* kp = Kb + (((size_t)bh * TT) + t) * DD + g * 16;
    union U8 { uint4 v; unsigned short s[8]; } k0v, k1v, o0, o1;
    k0v.v = *(const uint4*)kp;
    k1v.v = *(const uint4*)(kp + 8);
    const float* rp = rope + (size_t)t * 64 + g * 16;
#pragma unroll
    for (int uu = 0; uu < 8; ++uu) {
        float c = rp[2 * uu], sn = rp[2 * uu + 1];
        unsigned short ev = (uu < 4) ? k0v.s[2 * uu]     : k1v.s[2 * uu - 8];
        unsigned short ov = (uu < 4) ? k0v.s[2 * uu + 1] : k1v.s[2 * uu - 7];
        float f0 = bf2f(ev), f1 = bf2f(ov);
        unsigned int pr = bf16pair(f0 * c - f1 * sn, f1 * c + f0 * sn);
        if (uu < 4) ((unsigned int*)&o0)[uu] = pr;
        else        ((unsigned int*)&o1)[uu - 4] = pr;
    }
    *(uint4*)kp = o0.v;
    *(uint4*)(kp + 8) = o1.v;
}

// ------------------------ LDS-staged MFMA flash attention, double-buffered.
// Grid 1024 = 4 blocks/CU (LDS exactly 40960 B); balanced per-CU qblk sets
// {v, 15-v, 16+v, 31-v} = 66 tiles. One barrier per tile.
// P strip: stride-64 shorts with 16B XOR swizzle. Q roped in-register.
__global__ __launch_bounds__(256, 4) void attn_mfma10(
    const __hip_bfloat16* __restrict__ Qb, const __hip_bfloat16* __restrict__ Kb,
    const __hip_bfloat16* __restrict__ Vtb, const float* __restrict__ rope,
    __hip_bfloat16* __restrict__ out, float* __restrict__ osq) {
    const float QSC = 0.125f * 1.44269504f;
    int i = blockIdx.x;
    int xcd = i & 7;
    int r0 = i >> 3;                 // 0..127
    int bh = xcd + 8 * (r0 & 3);     // 4 bh per XCD (L2 locality)
    int rr = r0 >> 2;                // 0..31
    int v = rr & 7, s2 = rr >> 3;
    int qblk = (s2 == 0) ? v : (s2 == 1) ? (15 - v) : (s2 == 2) ? (16 + v) : (31 - v);
    int b = bh >> 4, h = bh & 15;
    int tid = threadIdx.x;
    int wave = tid >> 6, lane = tid & 63, quad = lane >> 4, l16 = lane & 15;

    __shared__ __align__(16) unsigned short Ks[2][2][64 * 32];   // 16384 B
    __shared__ __align__(16) unsigned short Vs[2][2][64 * 32];   // 16384 B
    __shared__ __align__(16) unsigned short Ps[4][16 * 64];      //  8192 B -> 40960 total
    unsigned short* pp = &Ps[wave][0];
    int sw = l16 & 7;                // XOR swizzle key (16B-chunk granularity)

    const __hip_bfloat16* Qbase = Qb + (size_t)bh * TT * DD;
    const __hip_bfloat16* Kbase = Kb + (size_t)bh * TT * DD;
    const __hip_bfloat16* Vbase = Vtb + (size_t)bh * DD * TT;

    int qw = qblk * 64 + wave * 16;
    // Q load + in-register rope (scaled by QSC)
    short8 qf0, qf1;
    {
        int t = qw + l16;
        const unsigned short* qr = (const unsigned short*)(Qbase + (size_t)t * DD) + quad * 8;
        union S8 { short8 v; unsigned short s[8]; } r0v, r1v, o0v, o1v;
        r0v.v = *(const short8*)qr;
        r1v.v = *(const short8*)(qr + 32);
        const float* rpa = rope + (size_t)t * 64 + quad * 8;
        const float* rpb = rpa + 32;
#pragma unroll
        for (int u = 0; u < 4; ++u) {
            float c = rpa[2 * u] * QSC, sn = rpa[2 * u + 1] * QSC;
            float e = bf2f(r0v.s[2 * u]), o = bf2f(r0v.s[2 * u + 1]);
            ((unsigned int*)&o0v)[u] = bf16pair(e * c - o * sn, o * c + e * sn);
            float c2 = rpb[2 * u] * QSC, sn2 = rpb[2 * u + 1] * QSC;
            float e2 = bf2f(r1v.s[2 * u]), o2 = bf2f(r1v.s[2 * u + 1]);
            ((unsigned int*)&o1v)[u] = bf16pair(e2 * c2 - o2 * sn2, o2 * c2 + e2 * sn2);
        }
        qf0 = o0v.v;
        qf1 = o1v.v;
    }
    short8 ones8;
#pragma unroll
    for (int u = 0; u < 8; ++u) ones8[u] = (short)0x3F80;   // bf16 1.0

    f32x4 acc_o[4];
#pragma unroll
    for (int mt = 0; mt < 4; ++mt) acc_o[mt] = f32x4{0.f, 0.f, 0.f, 0.f};
    f32x4 acc_l = {0.f, 0.f, 0.f, 0.f};

    int srow = lane >> 2, soff = (lane & 3) * 8;
    int q_g = qw + l16;

    // stage tile 0 into buffer 0
    gl_lds16(Kbase + (size_t)(wave * 16 + srow) * DD + soff,      &Ks[0][0][wave * 512]);
    gl_lds16(Kbase + (size_t)(wave * 16 + srow) * DD + 32 + soff, &Ks[0][1][wave * 512]);
    gl_lds16(Vbase + (size_t)(wave * 16 + srow) * TT + soff,      &Vs[0][0][wave * 512]);
    gl_lds16(Vbase + (size_t)(wave * 16 + srow) * TT + 32 + soff, &Vs[0][1][wave * 512]);

    for (int kt = 0; kt <= qblk; ++kt) {
        int cur = kt & 1;
        int k0 = kt * 64;
        __syncthreads();       // staging of buf cur complete; compute kt-1 done
        if (kt < qblk) {       // prefetch next tile into other buffer
            int nb = cur ^ 1, kn = k0 + 64;
            gl_lds16(Kbase + (size_t)(kn + wave * 16 + srow) * DD + soff,      &Ks[nb][0][wave * 512]);
            gl_lds16(Kbase + (size_t)(kn + wave * 16 + srow) * DD + 32 + soff, &Ks[nb][1][wave * 512]);
            gl_lds16(Vbase + (size_t)(wave * 16 + srow) * TT + kn + soff,      &Vs[nb][0][wave * 512]);
            gl_lds16(Vbase + (size_t)(wave * 16 + srow) * TT + kn + 32 + soff, &Vs[nb][1][wave * 512]);
        }
        // S^T = K·Q^T
        f32x4 accs[4];
#pragma unroll
        for (int mt = 0; mt < 4; ++mt) {
            short8 kf0 = *(const short8*)(&Ks[cur][0][(mt * 16 + l16) * 32 + quad * 8]);
            short8 kf1 = *(const short8*)(&Ks[cur][1][(mt * 16 + l16) * 32 + quad * 8]);
            f32x4 z = {0.f, 0.f, 0.f, 0.f};
            z = __builtin_amdgcn_mfma_f32_16x16x32_bf16(kf0, qf0, z, 0, 0, 0);
            accs[mt] = __builtin_amdgcn_mfma_f32_16x16x32_bf16(kf1, qf1, z, 0, 0, 0);
        }
        int limit = (kt == qblk) ? q_g : 0x7FFFFFFF;
#pragma unroll
        for (int mt = 0; mt < 4; ++mt) {
            int keyb = k0 + mt * 16 + quad * 4;
            float p0 = exp2f(accs[mt][0]);
            float p1 = exp2f(accs[mt][1]);
            float p2 = exp2f(accs[mt][2]);
            float p3 = exp2f(accs[mt][3]);
            p0 = (keyb + 0 <= limit) ? p0 : 0.f;
            p1 = (keyb + 1 <= limit) ? p1 : 0.f;
            p2 = (keyb + 2 <= limit) ? p2 : 0.f;
            p3 = (keyb + 3 <= limit) ? p3 : 0.f;
            uint2 w2;
            w2.x = bf16pair(p0, p1);
            w2.y = bf16pair(p2, p3);
            int off = (((mt * 2 + (quad >> 1)) ^ sw) << 3) + ((quad & 1) << 2);
            *(uint2*)(pp + (l16 << 6) + off) = w2;
        }
        short8 pf0 = *(const short8*)(pp + (l16 << 6) + ((quad ^ sw) << 3));
        short8 pf1 = *(const short8*)(pp + (l16 << 6) + (((4 + quad) ^ sw) << 3));
        // O^T += V^T·P^T
#pragma unroll
        for (int mt = 0; mt < 4; ++mt) {
            short8 vf0 = *(const short8*)(&Vs[cur][0][(mt * 16 + l16) * 32 + quad * 8]);
            short8 vf1 = *(const short8*)(&Vs[cur][1][(mt * 16 + l16) * 32 + quad * 8]);
            acc_o[mt] = __builtin_amdgcn_mfma_f32_16x16x32_bf16(vf0, pf0, acc_o[mt], 0, 0, 0);
            acc_o[mt] = __builtin_amdgcn_mfma_f32_16x16x32_bf16(vf1, pf1, acc_o[mt], 0, 0, 0);
        }
        acc_l = __builtin_amdgcn_mfma_f32_16x16x32_bf16(ones8, pf0, acc_l, 0, 0, 0);
        acc_l = __builtin_amdgcn_mfma_f32_16x16x32_bf16(ones8, pf1, acc_l, 0, 0, 0);
    }
    // epilogue: normalize (row sum from acc_l), osq, transpose via Ps, store
    float inv = 1.f / acc_l[0];
    float part = 0.f;
#pragma unroll
    for (int mt = 0; mt < 4; ++mt) {
        float o0 = acc_o[mt][0] * inv;
        float o1 = acc_o[mt][1] * inv;
        float o2 = acc_o[mt][2] * inv;
        float o3 = acc_o[mt][3] * inv;
        part += o0 * o0 + o1 * o1 + o2 * o2 + o3 * o3;
        uint2 w2;
        w2.x = bf16pair(o0, o1);
        w2.y = bf16pair(o2, o3);
        int off = (((mt * 2 + (quad >> 1)) ^ sw) << 3) + ((quad & 1) << 2);
        *(uint2*)(pp + (l16 << 6) + off) = w2;   // O[q=l16][d], swizzled
    }
    part += __shfl_xor(part, 16, 64);
    part += __shfl_xor(part, 32, 64);
    if (quad == 0) atomicAdd(&osq[(size_t)b * TT + qw + l16], part);
    int rw = lane >> 2, cg = lane & 3, sw2 = rw & 7;
    uint4 o0 = *(const uint4*)(pp + (rw << 6) + (((cg * 2) ^ sw2) << 3));
    uint4 o1 = *(const uint4*)(pp + (rw << 6) + (((cg * 2 + 1) ^ sw2) << 3));
    __hip_bfloat16* orow = out + (size_t)(b * TT + qw + rw) * CC + h * DD + cg * 16;
    *(uint4*)(orow) = o0;
    *(uint4*)(orow + 8) = o1;
}

// ----------------- gemm2: MFMA bf16 GEMM, BK=64, yat epilogue
template<int TM, int TN, typename OutT>
__global__ __launch_bounds__(256) void yat_gemm_bk64(
    const __hip_bfloat16* __restrict__ A,
    const __hip_bfloat16* __restrict__ Bt,
    const float* __restrict__ xsq, const float* __restrict__ wsq,
    const float* __restrict__ bias, OutT* __restrict__ C,
    int M, int N, int K, float scale) {
    constexpr int MT = TM / 32;
    constexpr int NT = TN / 32;
    constexpr int IA = TM / 64;
    constexpr int IB = TN / 64;
    __shared__ __align__(16) unsigned short As0[TM * 32];
    __shared__ __align__(16) unsigned short As1[TM * 32];
    __shared__ __align__(16) unsigned short Bs0[TN * 32];
    __shared__ __align__(16) unsigned short Bs1[TN * 32];
    int tid = threadIdx.x;
    int wave = tid >> 6, lane = tid & 63, quad = lane >> 4, l16 = lane & 15;
    int wr = wave >> 1, wc = wave & 1;
    int m0 = blockIdx.y * TM, n0 = blockIdx.x * TN;

    f32x4 acc[MT][NT];
#pragma unroll
    for (int mt = 0; mt < MT; ++mt)
#pragma unroll
        for (int nt = 0; nt < NT; ++nt) acc[mt][nt] = f32x4{0.f, 0.f, 0.f, 0.f};

    int srow = lane >> 2, soff = (lane & 3) << 3;
    for (int k0 = 0; k0 < K; k0 += 64) {
        __syncthreads();
#pragma unroll
        for (int i = 0; i < IA; ++i) {
            int rowc = (wave * IA + i) * 16;
            const __hip_bfloat16* ap = A + (size_t)(m0 + rowc + srow) * K + k0 + soff;
            gl_lds16(ap,      As0 + rowc * 32);
            gl_lds16(ap + 32, As1 + rowc * 32);
        }
#pragma unroll
        for (int i = 0; i < IB; ++i) {
            int rowc = (wave * IB + i) * 16;
            const __hip_bfloat16* bp = Bt + (size_t)(n0 + rowc + srow) * K + k0 + soff;
            gl_lds16(bp,      Bs0 + rowc * 32);
            gl_lds16(bp + 32, Bs1 + rowc * 32);
        }
        __syncthreads();
#pragma unroll
        for (int h = 0; h < 2; ++h) {
            const unsigned short* Ah = h ? As1 : As0;
            const unsigned short* Bh = h ? Bs1 : Bs0;
            short8 af[MT], bf[NT];
#pragma unroll
            for (int mt = 0; mt < MT; ++mt)
                af[mt] = *(const short8*)(Ah + (wr * (TM / 2) + mt * 16 + l16) * 32 + quad * 8);
#pragma unroll
            for (int nt = 0; nt < NT; ++nt)
                bf[nt] = *(const short8*)(Bh + (wc * (TN / 2) + nt * 16 + l16) * 32 + quad * 8);
#pragma unroll
            for (int mt = 0; mt < MT; ++mt)
#pragma unroll
                for (int nt = 0; nt < NT; ++nt)
                    acc[mt][nt] = __builtin_amdgcn_mfma_f32_16x16x32_bf16(af[mt], bf[nt], acc[mt][nt], 0, 0, 0);
        }
    }
    int mb = m0 + wr * (TM / 2) + quad * 4;
#pragma unroll
    for (int nt = 0; nt < NT; ++nt) {
        int col = n0 + wc * (TN / 2) + nt * 16 + l16;
        float wq = wsq[col];
        float bs = bias[col];
#pragma unroll
        for (int mt = 0; mt < MT; ++mt) {
#pragma unroll
            for (int r = 0; r < 4; ++r) {
                int row = mb + mt * 16 + r;
                float dot = acc[mt][nt][r];
                float dist = xsq[row] + wq - 2.f * dot + EPS;
                C[(size_t)row * N + col] = (OutT)(dot * dot / dist * scale + bs);
            }
        }
    }
}

// ---------------------------------------------------------------- launcher
extern "C" void kernel_launch(void* const* d_in, const int* in_sizes, int n_in,
                              void* d_out, int out_size, void* d_ws, size_t ws_size,
                              hipStream_t stream) {
    const float* x      = (const float*)d_in[0];
    // d_in[1] = mask (causal tril) — implied analytically, unused
    const float* w_attn = (const float*)d_in[2];
    const float* b_attn = (const float*)d_in[3];
    const float* w_proj = (const float*)d_in[4];
    const float* b_proj = (const float*)d_in[5];
    float* out = (float*)d_out;

    char* ws = (char*)d_ws;
    __hip_bfloat16* xbf  = (__hip_bfloat16*)(ws + 0);         // 8 MB
    __hip_bfloat16* aout = (__hip_bfloat16*)(ws + 8388608);   // 8 MB
    __hip_bfloat16* watT = (__hip_bfloat16*)(ws + 16777216);  // 6 MB
    __hip_bfloat16* wpT  = (__hip_bfloat16*)(ws + 23068672);  // 2 MB
    float*          rope = (float*)(ws + 25165824);           // 512 KB
    float*          xsq  = (float*)(ws + 25690112);           // 16 KB
    float*          osq  = (float*)(ws + 25706496);           // 16 KB
    float*          wsqa = (float*)(ws + 25722880);           // 12 KB
    float*          wsqp = (float*)(ws + 25735168);           // 4 KB
    __hip_bfloat16* Qb   = (__hip_bfloat16*)(ws + 25739264);  // 8 MB [bh][t][d]
    __hip_bfloat16* Kb   = (__hip_bfloat16*)(ws + 34127872);  // 8 MB [bh][t][d]
    __hip_bfloat16* Vtb  = (__hip_bfloat16*)(ws + 42516480);  // 8 MB [bh][d][t]

    float scale1 = (float)(sqrt(3072.0) / log1p(3072.0));
    float scale2 = (float)(sqrt(1024.0) / log1p(1024.0));

    prep_all2<<<64 + ROWS + 256, 256, 0, stream>>>(
        x, xsq, xbf, osq, rope, w_attn, watT, wsqa, w_proj, wpT, wsqp);
    yat_gemm_qkv3<<<dim3(N1 / 128, ROWS / 128), 256, 0, stream>>>(
        xbf, watT, xsq, wsqa, b_attn, Qb, Kb, Vtb, scale1);
    ropek<<<1024, 256, 0, stream>>>((unsigned short*)Kb, rope);
    attn_mfma10<<<1024, 256, 0, stream>>>(Qb, Kb, Vtb, rope, aout, osq);
    yat_gemm_bk64<64, 64, float><<<dim3(CC / 64, ROWS / 64), 256, 0, stream>>>(
        aout, wpT, osq, wsqp, b_proj, out, ROWS, CC, CC, scale2);
}

// Round 15
// 219.906 us; speedup vs baseline: 1.0904x; 1.0904x over previous
//
#include <hip/hip_runtime.h>
#include <hip/hip_bf16.h>
#include <cmath>
#include <type_traits>

// Problem constants
#define BB 2
#define TT 2048
#define CC 1024
#define HH 16
#define DD 64
#define ROWS (BB*TT)          // 4096
#define N1 (3*CC)             // 3072
#define EPS 1e-6f

using short8 = __attribute__((ext_vector_type(8))) short;
using f32x4  = __attribute__((ext_vector_type(4))) float;

__device__ __forceinline__ void gl_lds16(const __hip_bfloat16* g, unsigned short* l) {
    __builtin_amdgcn_global_load_lds(
        (const __attribute__((address_space(1))) unsigned int*)(g),
        (__attribute__((address_space(3))) unsigned int*)(l), 16, 0, 0);
}

__device__ __forceinline__ unsigned int bf16pair(float a, float b) {
    __hip_bfloat16 ha = (__hip_bfloat16)a, hb = (__hip_bfloat16)b;  // RNE
    unsigned short ua = *(unsigned short*)&ha, ub = *(unsigned short*)&hb;
    return (unsigned int)ua | ((unsigned int)ub << 16);
}

__device__ __forceinline__ float bf2f(unsigned short u) {
    unsigned int v = (unsigned int)u << 16;
    return *(float*)&v;
}

// -------- aux1: row sum-of-squares + bf16 cast + rope table + zero inits
__global__ void aux_rowsq(const float* __restrict__ X, float* __restrict__ xsq,
                          __hip_bfloat16* __restrict__ Xb, float* __restrict__ osq,
                          float* __restrict__ rope,
                          float* __restrict__ wsqa, float* __restrict__ wsqp) {
    int blk = blockIdx.x;
    int t = threadIdx.x;
    if (blk >= ROWS) {      // tail blocks: rope table + zero inits
        int idx = (blk - ROWS) * 256 + t;
        if (idx < N1) wsqa[idx] = 0.f;
        if (idx < CC) wsqp[idx] = 0.f;
        if (idx < TT * 32) {
            int tt = idx >> 5, i = idx & 31;
            double freq = pow(10000.0, -(double)i / 32.0);
            float ang = (float)tt * (float)freq;
            rope[idx * 2 + 0] = cosf(ang);
            rope[idx * 2 + 1] = sinf(ang);
        }
        return;
    }
    int row = blk;
    const float* xr = X + (size_t)row * CC;
    __hip_bfloat16* br = Xb + (size_t)row * CC;
    float p = 0.f;
#pragma unroll
    for (int i = 0; i < 4; ++i) {
        float v = xr[t + i * 256];
        p += v * v;
        br[t + i * 256] = (__hip_bfloat16)v;
    }
#pragma unroll
    for (int off = 32; off > 0; off >>= 1) p += __shfl_xor(p, off, 64);
    __shared__ float s4[4];
    if ((t & 63) == 0) s4[t >> 6] = p;
    __syncthreads();
    if (t == 0) { xsq[row] = s4[0] + s4[1] + s4[2] + s4[3]; osq[row] = 0.f; }
}

// ---------- fused transpose of both weights: W (KxN fp32) -> Wt (NxK bf16) + colsq
__global__ void transpose2(const float* __restrict__ Wa, __hip_bfloat16* __restrict__ WaT,
                           float* __restrict__ wsqa,
                           const float* __restrict__ Wp, __hip_bfloat16* __restrict__ WpT,
                           float* __restrict__ wsqp) {
    const float* W; __hip_bfloat16* Wt; float* wsq; int N;
    if (blockIdx.z == 0) { W = Wa; Wt = WaT; wsq = wsqa; N = N1; }
    else { if (blockIdx.x >= 16) return; W = Wp; Wt = WpT; wsq = wsqp; N = CC; }
    const int K = CC;
    __shared__ unsigned short tile[64][65];
    int n0 = blockIdx.x * 64, k0 = blockIdx.y * 64;
    int c = threadIdx.x & 63, rg = threadIdx.x >> 6;
    float part = 0.f;
#pragma unroll
    for (int rr = 0; rr < 16; ++rr) {
        int r = rg + rr * 4;
        float f = W[(size_t)(k0 + r) * N + n0 + c];
        __hip_bfloat16 h = (__hip_bfloat16)f;
        tile[r][c] = *(unsigned short*)&h;
        part += f * f;
    }
    atomicAdd(&wsq[n0 + c], part);
    __syncthreads();
#pragma unroll
    for (int rr = 0; rr < 16; ++rr) {
        int r = rg + rr * 4;
        unsigned short u = tile[c][r];
        Wt[(size_t)(n0 + r) * K + k0 + c] = *(__hip_bfloat16*)&u;
    }
}

// --------- gemm1: x @ w_attn, yat epilogue, scatter to Qb/Kb/Vb [bh][t][d]
// 128x128 tile, BK=64. NO rope (done by consumers). Clean per-element scatter
// (epilogue complexity costs VGPR/occupancy — rounds 9 & 14 both regressed).
__global__ __launch_bounds__(256) void yat_gemm_qkv2(
    const __hip_bfloat16* __restrict__ A,
    const __hip_bfloat16* __restrict__ Bt,
    const float* __restrict__ xsq, const float* __restrict__ wsq,
    const float* __restrict__ bias,
    __hip_bfloat16* __restrict__ Qb, __hip_bfloat16* __restrict__ Kb,
    __hip_bfloat16* __restrict__ Vb, float scale) {
    const int K = CC;
    __shared__ __align__(16) unsigned short As0[128 * 32], As1[128 * 32];
    __shared__ __align__(16) unsigned short Bs0[128 * 32], Bs1[128 * 32];
    int tid = threadIdx.x;
    int wave = tid >> 6, lane = tid & 63, quad = lane >> 4, l16 = lane & 15;
    int wr = wave >> 1, wc = wave & 1;
    int m0 = blockIdx.y * 128, n0 = blockIdx.x * 128;

    f32x4 acc[4][4];
#pragma unroll
    for (int mt = 0; mt < 4; ++mt)
#pragma unroll
        for (int nt = 0; nt < 4; ++nt) acc[mt][nt] = f32x4{0.f, 0.f, 0.f, 0.f};

    int srow = lane >> 2, soff = (lane & 3) << 3;
    for (int k0 = 0; k0 < K; k0 += 64) {
        __syncthreads();
#pragma unroll
        for (int i = 0; i < 2; ++i) {
            int rowc = (wave * 2 + i) * 16;
            const __hip_bfloat16* ap = A + (size_t)(m0 + rowc + srow) * K + k0 + soff;
            gl_lds16(ap,      As0 + rowc * 32);
            gl_lds16(ap + 32, As1 + rowc * 32);
            const __hip_bfloat16* bp = Bt + (size_t)(n0 + rowc + srow) * K + k0 + soff;
            gl_lds16(bp,      Bs0 + rowc * 32);
            gl_lds16(bp + 32, Bs1 + rowc * 32);
        }
        __syncthreads();
#pragma unroll
        for (int h = 0; h < 2; ++h) {
            const unsigned short* Ah = h ? As1 : As0;
            const unsigned short* Bh = h ? Bs1 : Bs0;
            short8 af[4], bf[4];
#pragma unroll
            for (int mt = 0; mt < 4; ++mt)
                af[mt] = *(const short8*)(Ah + (wr * 64 + mt * 16 + l16) * 32 + quad * 8);
#pragma unroll
            for (int nt = 0; nt < 4; ++nt)
                bf[nt] = *(const short8*)(Bh + (wc * 64 + nt * 16 + l16) * 32 + quad * 8);
#pragma unroll
            for (int mt = 0; mt < 4; ++mt)
#pragma unroll
                for (int nt = 0; nt < 4; ++nt)
                    acc[mt][nt] = __builtin_amdgcn_mfma_f32_16x16x32_bf16(af[mt], bf[nt], acc[mt][nt], 0, 0, 0);
        }
    }
    int mb = m0 + wr * 64 + quad * 4;
#pragma unroll
    for (int nt = 0; nt < 4; ++nt) {
        int col = n0 + wc * 64 + nt * 16 + l16;
        float wq = wsq[col], bs = bias[col];
        int sec = col >> 10, cc2 = col & 1023;
        int h = cc2 >> 6, d = cc2 & 63;
        __hip_bfloat16* dst = (sec == 0) ? Qb : ((sec == 1) ? Kb : Vb);
#pragma unroll
        for (int mt = 0; mt < 4; ++mt) {
#pragma unroll
            for (int r = 0; r < 4; ++r) {
                int row = mb + mt * 16 + r;
                float dot = acc[mt][nt][r];
                float dist = xsq[row] + wq - 2.f * dot + EPS;
                float y = dot * dot / dist * scale + bs;
                int t = row & (TT - 1), bI = row >> 11;
                dst[(((size_t)bI * HH + h) * TT + t) * DD + d] = (__hip_bfloat16)y;
            }
        }
    }
}

// ------------- rope K in place + transpose V: Vb [bh][t][d] -> Vtb [bh][d][t]
__global__ __launch_bounds__(256) void ropek_vtrans(
    unsigned short* __restrict__ Kb, const unsigned short* __restrict__ Vb,
    __hip_bfloat16* __restrict__ Vtb, const float* __restrict__ rope) {
    int bh = blockIdx.y, t0 = blockIdx.x * 64, tid = threadIdx.x;
    __shared__ unsigned short vt[64][72];
    int r = tid >> 2, g = tid & 3;
    const unsigned short* src = Vb + ((size_t)bh * TT + t0 + r) * DD + g * 16;
    *(uint4*)&vt[r][g * 16]     = *(const uint4*)src;
    *(uint4*)&vt[r][g * 16 + 8] = *(const uint4*)(src + 8);
    {
        int t = t0 + r;
        unsigned short* kp = Kb + ((size_t)bh * TT + t) * DD + g * 16;
        union U8 { uint4 v; unsigned short s[8]; } k0v, k1v, o0, o1;
        k0v.v = *(const uint4*)kp;
        k1v.v = *(const uint4*)(kp + 8);
        const float* rp = rope + (size_t)t * 64 + g * 16;
#pragma unroll
        for (int u = 0; u < 8; ++u) {
            float c = rp[2 * u], sn = rp[2 * u + 1];
            unsigned short ev = (u < 4) ? k0v.s[2 * u]     : k1v.s[2 * u - 8];
            unsigned short ov = (u < 4) ? k0v.s[2 * u + 1] : k1v.s[2 * u - 7];
            float f0 = bf2f(ev), f1 = bf2f(ov);
            unsigned int pr = bf16pair(f0 * c - f1 * sn, f1 * c + f0 * sn);
            if (u < 4) ((unsigned int*)&o0)[u] = pr;
            else       ((unsigned int*)&o1)[u - 4] = pr;
        }
        *(uint4*)kp = o0.v;
        *(uint4*)(kp + 8) = o1.v;
    }
    __syncthreads();
    union U8b { uint4 v; unsigned short s[8]; };
#pragma unroll
    for (int p = 0; p < 2; ++p) {
        int d = (tid >> 3) + p * 32, tl = (tid & 7) * 8;
        U8b w;
#pragma unroll
        for (int j = 0; j < 8; ++j) w.s[j] = vt[tl + j][d];
        *(uint4*)(Vtb + ((size_t)bh * DD + d) * TT + t0 + tl) = w.v;
    }
}

// ------------------------ LDS-staged MFMA flash attention, double-buffered.
// Grid 1024 = 4 blocks/CU (LDS exactly 40960 B); balanced per-CU qblk sets
// {v, 15-v, 16+v, 31-v} = 66 tiles. One barrier per tile. Diagonal tile split
// out of the main loop (mask VALU only on 1 of ~17 tiles).
// P strip: stride-64 shorts with 16B XOR swizzle. Q roped in-register.
__global__ __launch_bounds__(256, 4) void attn_mfma11(
    const __hip_bfloat16* __restrict__ Qb, const __hip_bfloat16* __restrict__ Kb,
    const __hip_bfloat16* __restrict__ Vtb, const float* __restrict__ rope,
    __hip_bfloat16* __restrict__ out, float* __restrict__ osq) {
    const float QSC = 0.125f * 1.44269504f;
    int i = blockIdx.x;
    int xcd = i & 7;
    int r0 = i >> 3;                 // 0..127
    int bh = xcd + 8 * (r0 & 3);     // 4 bh per XCD (L2 locality)
    int rr = r0 >> 2;                // 0..31
    int v = rr & 7, s2 = rr >> 3;
    int qblk = (s2 == 0) ? v : (s2 == 1) ? (15 - v) : (s2 == 2) ? (16 + v) : (31 - v);
    int b = bh >> 4, h = bh & 15;
    int tid = threadIdx.x;
    int wave = tid >> 6, lane = tid & 63, quad = lane >> 4, l16 = lane & 15;

    __shared__ __align__(16) unsigned short Ks[2][2][64 * 32];   // 16384 B
    __shared__ __align__(16) unsigned short Vs[2][2][64 * 32];   // 16384 B
    __shared__ __align__(16) unsigned short Ps[4][16 * 64];      //  8192 B -> 40960 total
    unsigned short* pp = &Ps[wave][0];
    int sw = l16 & 7;                // XOR swizzle key (16B-chunk granularity)

    const __hip_bfloat16* Qbase = Qb + (size_t)bh * TT * DD;
    const __hip_bfloat16* Kbase = Kb + (size_t)bh * TT * DD;
    const __hip_bfloat16* Vbase = Vtb + (size_t)bh * DD * TT;

    int qw = qblk * 64 + wave * 16;
    // Q load + in-register rope (scaled by QSC)
    short8 qf0, qf1;
    {
        int t = qw + l16;
        const unsigned short* qr = (const unsigned short*)(Qbase + (size_t)t * DD) + quad * 8;
        union S8 { short8 v; unsigned short s[8]; } r0v, r1v, o0v, o1v;
        r0v.v = *(const short8*)qr;
        r1v.v = *(const short8*)(qr + 32);
        const float* rpa = rope + (size_t)t * 64 + quad * 8;
        const float* rpb = rpa + 32;
#pragma unroll
        for (int u = 0; u < 4; ++u) {
            float c = rpa[2 * u] * QSC, sn = rpa[2 * u + 1] * QSC;
            float e = bf2f(r0v.s[2 * u]), o = bf2f(r0v.s[2 * u + 1]);
            ((unsigned int*)&o0v)[u] = bf16pair(e * c - o * sn, o * c + e * sn);
            float c2 = rpb[2 * u] * QSC, sn2 = rpb[2 * u + 1] * QSC;
            float e2 = bf2f(r1v.s[2 * u]), o2 = bf2f(r1v.s[2 * u + 1]);
            ((unsigned int*)&o1v)[u] = bf16pair(e2 * c2 - o2 * sn2, o2 * c2 + e2 * sn2);
        }
        qf0 = o0v.v;
        qf1 = o1v.v;
    }
    short8 ones8;
#pragma unroll
    for (int u = 0; u < 8; ++u) ones8[u] = (short)0x3F80;   // bf16 1.0

    f32x4 acc_o[4];
#pragma unroll
    for (int mt = 0; mt < 4; ++mt) acc_o[mt] = f32x4{0.f, 0.f, 0.f, 0.f};
    f32x4 acc_l = {0.f, 0.f, 0.f, 0.f};

    int srow = lane >> 2, soff = (lane & 3) * 8;
    int q_g = qw + l16;

    // tile body: compute on buffer `cur` for keys [k0, k0+64)
    auto tile_body = [&](int cur, int k0, auto mc) {
        constexpr bool MASK = decltype(mc)::value;
        f32x4 accs[4];
#pragma unroll
        for (int mt = 0; mt < 4; ++mt) {
            short8 kf0 = *(const short8*)(&Ks[cur][0][(mt * 16 + l16) * 32 + quad * 8]);
            short8 kf1 = *(const short8*)(&Ks[cur][1][(mt * 16 + l16) * 32 + quad * 8]);
            f32x4 z = {0.f, 0.f, 0.f, 0.f};
            z = __builtin_amdgcn_mfma_f32_16x16x32_bf16(kf0, qf0, z, 0, 0, 0);
            accs[mt] = __builtin_amdgcn_mfma_f32_16x16x32_bf16(kf1, qf1, z, 0, 0, 0);
        }
#pragma unroll
        for (int mt = 0; mt < 4; ++mt) {
            int keyb = k0 + mt * 16 + quad * 4;
            float p0 = exp2f(accs[mt][0]);
            float p1 = exp2f(accs[mt][1]);
            float p2 = exp2f(accs[mt][2]);
            float p3 = exp2f(accs[mt][3]);
            if (MASK) {
                p0 = (keyb + 0 <= q_g) ? p0 : 0.f;
                p1 = (keyb + 1 <= q_g) ? p1 : 0.f;
                p2 = (keyb + 2 <= q_g) ? p2 : 0.f;
                p3 = (keyb + 3 <= q_g) ? p3 : 0.f;
            }
            uint2 w2;
            w2.x = bf16pair(p0, p1);
            w2.y = bf16pair(p2, p3);
            int off = (((mt * 2 + (quad >> 1)) ^ sw) << 3) + ((quad & 1) << 2);
            *(uint2*)(pp + (l16 << 6) + off) = w2;
        }
        short8 pf0 = *(const short8*)(pp + (l16 << 6) + ((quad ^ sw) << 3));
        short8 pf1 = *(const short8*)(pp + (l16 << 6) + (((4 + quad) ^ sw) << 3));
#pragma unroll
        for (int mt = 0; mt < 4; ++mt) {
            short8 vf0 = *(const short8*)(&Vs[cur][0][(mt * 16 + l16) * 32 + quad * 8]);
            short8 vf1 = *(const short8*)(&Vs[cur][1][(mt * 16 + l16) * 32 + quad * 8]);
            acc_o[mt] = __builtin_amdgcn_mfma_f32_16x16x32_bf16(vf0, pf0, acc_o[mt], 0, 0, 0);
            acc_o[mt] = __builtin_amdgcn_mfma_f32_16x16x32_bf16(vf1, pf1, acc_o[mt], 0, 0, 0);
        }
        acc_l = __builtin_amdgcn_mfma_f32_16x16x32_bf16(ones8, pf0, acc_l, 0, 0, 0);
        acc_l = __builtin_amdgcn_mfma_f32_16x16x32_bf16(ones8, pf1, acc_l, 0, 0, 0);
    };

    // stage tile 0 into buffer 0
    gl_lds16(Kbase + (size_t)(wave * 16 + srow) * DD + soff,      &Ks[0][0][wave * 512]);
    gl_lds16(Kbase + (size_t)(wave * 16 + srow) * DD + 32 + soff, &Ks[0][1][wave * 512]);
    gl_lds16(Vbase + (size_t)(wave * 16 + srow) * TT + soff,      &Vs[0][0][wave * 512]);
    gl_lds16(Vbase + (size_t)(wave * 16 + srow) * TT + 32 + soff, &Vs[0][1][wave * 512]);

    for (int kt = 0; kt < qblk; ++kt) {
        int cur = kt & 1;
        __syncthreads();       // staging of buf cur complete; compute kt-1 done
        {   // prefetch next tile (kt+1 <= qblk always exists here)
            int nb = cur ^ 1, kn = kt * 64 + 64;
            gl_lds16(Kbase + (size_t)(kn + wave * 16 + srow) * DD + soff,      &Ks[nb][0][wave * 512]);
            gl_lds16(Kbase + (size_t)(kn + wave * 16 + srow) * DD + 32 + soff, &Ks[nb][1][wave * 512]);
            gl_lds16(Vbase + (size_t)(wave * 16 + srow) * TT + kn + soff,      &Vs[nb][0][wave * 512]);
            gl_lds16(Vbase + (size_t)(wave * 16 + srow) * TT + kn + 32 + soff, &Vs[nb][1][wave * 512]);
        }
        tile_body(cur, kt * 64, std::integral_constant<bool, false>{});
    }
    __syncthreads();           // diagonal tile staged
    tile_body(qblk & 1, qblk * 64, std::integral_constant<bool, true>{});

    // epilogue: normalize (row sum from acc_l), osq, transpose via Ps, store
    float inv = 1.f / acc_l[0];
    float part = 0.f;
#pragma unroll
    for (int mt = 0; mt < 4; ++mt) {
        float o0 = acc_o[mt][0] * inv;
        float o1 = acc_o[mt][1] * inv;
        float o2 = acc_o[mt][2] * inv;
        float o3 = acc_o[mt][3] * inv;
        part += o0 * o0 + o1 * o1 + o2 * o2 + o3 * o3;
        uint2 w2;
        w2.x = bf16pair(o0, o1);
        w2.y = bf16pair(o2, o3);
        int off = (((mt * 2 + (quad >> 1)) ^ sw) << 3) + ((quad & 1) << 2);
        *(uint2*)(pp + (l16 << 6) + off) = w2;   // O[q=l16][d], swizzled
    }
    part += __shfl_xor(part, 16, 64);
    part += __shfl_xor(part, 32, 64);
    if (quad == 0) atomicAdd(&osq[(size_t)b * TT + qw + l16], part);
    int rw = lane >> 2, cg = lane & 3, sw2 = rw & 7;
    uint4 o0 = *(const uint4*)(pp + (rw << 6) + (((cg * 2) ^ sw2) << 3));
    uint4 o1 = *(const uint4*)(pp + (rw << 6) + (((cg * 2 + 1) ^ sw2) << 3));
    __hip_bfloat16* orow = out + (size_t)(b * TT + qw + rw) * CC + h * DD + cg * 16;
    *(uint4*)(orow) = o0;
    *(uint4*)(orow + 8) = o1;
}

// ----------------- gemm2: MFMA bf16 GEMM, BK=64, yat epilogue
template<int TM, int TN, typename OutT>
__global__ __launch_bounds__(256) void yat_gemm_bk64(
    const __hip_bfloat16* __restrict__ A,
    const __hip_bfloat16* __restrict__ Bt,
    const float* __restrict__ xsq, const float* __restrict__ wsq,
    const float* __restrict__ bias, OutT* __restrict__ C,
    int M, int N, int K, float scale) {
    constexpr int MT = TM / 32;
    constexpr int NT = TN / 32;
    constexpr int IA = TM / 64;
    constexpr int IB = TN / 64;
    __shared__ __align__(16) unsigned short As0[TM * 32];
    __shared__ __align__(16) unsigned short As1[TM * 32];
    __shared__ __align__(16) unsigned short Bs0[TN * 32];
    __shared__ __align__(16) unsigned short Bs1[TN * 32];
    int tid = threadIdx.x;
    int wave = tid >> 6, lane = tid & 63, quad = lane >> 4, l16 = lane & 15;
    int wr = wave >> 1, wc = wave & 1;
    int m0 = blockIdx.y * TM, n0 = blockIdx.x * TN;

    f32x4 acc[MT][NT];
#pragma unroll
    for (int mt = 0; mt < MT; ++mt)
#pragma unroll
        for (int nt = 0; nt < NT; ++nt) acc[mt][nt] = f32x4{0.f, 0.f, 0.f, 0.f};

    int srow = lane >> 2, soff = (lane & 3) << 3;
    for (int k0 = 0; k0 < K; k0 += 64) {
        __syncthreads();
#pragma unroll
        for (int i = 0; i < IA; ++i) {
            int rowc = (wave * IA + i) * 16;
            const __hip_bfloat16* ap = A + (size_t)(m0 + rowc + srow) * K + k0 + soff;
            gl_lds16(ap,      As0 + rowc * 32);
            gl_lds16(ap + 32, As1 + rowc * 32);
        }
#pragma unroll
        for (int i = 0; i < IB; ++i) {
            int rowc = (wave * IB + i) * 16;
            const __hip_bfloat16* bp = Bt + (size_t)(n0 + rowc + srow) * K + k0 + soff;
            gl_lds16(bp,      Bs0 + rowc * 32);
            gl_lds16(bp + 32, Bs1 + rowc * 32);
        }
        __syncthreads();
#pragma unroll
        for (int h = 0; h < 2; ++h) {
            const unsigned short* Ah = h ? As1 : As0;
            const unsigned short* Bh = h ? Bs1 : Bs0;
            short8 af[MT], bf[NT];
#pragma unroll
            for (int mt = 0; mt < MT; ++mt)
                af[mt] = *(const short8*)(Ah + (wr * (TM / 2) + mt * 16 + l16) * 32 + quad * 8);
#pragma unroll
            for (int nt = 0; nt < NT; ++nt)
                bf[nt] = *(const short8*)(Bh + (wc * (TN / 2) + nt * 16 + l16) * 32 + quad * 8);
#pragma unroll
            for (int mt = 0; mt < MT; ++mt)
#pragma unroll
                for (int nt = 0; nt < NT; ++nt)
                    acc[mt][nt] = __builtin_amdgcn_mfma_f32_16x16x32_bf16(af[mt], bf[nt], acc[mt][nt], 0, 0, 0);
        }
    }
    int mb = m0 + wr * (TM / 2) + quad * 4;
#pragma unroll
    for (int nt = 0; nt < NT; ++nt) {
        int col = n0 + wc * (TN / 2) + nt * 16 + l16;
        float wq = wsq[col];
        float bs = bias[col];
#pragma unroll
        for (int mt = 0; mt < MT; ++mt) {
#pragma unroll
            for (int r = 0; r < 4; ++r) {
                int row = mb + mt * 16 + r;
                float dot = acc[mt][nt][r];
                float dist = xsq[row] + wq - 2.f * dot + EPS;
                C[(size_t)row * N + col] = (OutT)(dot * dot / dist * scale + bs);
            }
        }
    }
}

// ---------------------------------------------------------------- launcher
extern "C" void kernel_launch(void* const* d_in, const int* in_sizes, int n_in,
                              void* d_out, int out_size, void* d_ws, size_t ws_size,
                              hipStream_t stream) {
    const float* x      = (const float*)d_in[0];
    // d_in[1] = mask (causal tril) — implied analytically, unused
    const float* w_attn = (const float*)d_in[2];
    const float* b_attn = (const float*)d_in[3];
    const float* w_proj = (const float*)d_in[4];
    const float* b_proj = (const float*)d_in[5];
    float* out = (float*)d_out;

    char* ws = (char*)d_ws;
    __hip_bfloat16* xbf  = (__hip_bfloat16*)(ws + 0);         // 8 MB
    __hip_bfloat16* aout = (__hip_bfloat16*)(ws + 8388608);   // 8 MB
    __hip_bfloat16* watT = (__hip_bfloat16*)(ws + 16777216);  // 6 MB
    __hip_bfloat16* wpT  = (__hip_bfloat16*)(ws + 23068672);  // 2 MB
    float*          rope = (float*)(ws + 25165824);           // 512 KB
    float*          xsq  = (float*)(ws + 25690112);           // 16 KB
    float*          osq  = (float*)(ws + 25706496);           // 16 KB
    float*          wsqa = (float*)(ws + 25722880);           // 12 KB
    float*          wsqp = (float*)(ws + 25735168);           // 4 KB
    __hip_bfloat16* Qb   = (__hip_bfloat16*)(ws + 25739264);  // 8 MB [bh][t][d]
    __hip_bfloat16* Kb   = (__hip_bfloat16*)(ws + 34127872);  // 8 MB [bh][t][d]
    __hip_bfloat16* Vb   = (__hip_bfloat16*)(ws + 42516480);  // 8 MB [bh][t][d]
    __hip_bfloat16* Vtb  = (__hip_bfloat16*)(ws + 50905088);  // 8 MB [bh][d][t]

    float scale1 = (float)(sqrt(3072.0) / log1p(3072.0));
    float scale2 = (float)(sqrt(1024.0) / log1p(1024.0));

    aux_rowsq<<<ROWS + 256, 256, 0, stream>>>(x, xsq, xbf, osq, rope, wsqa, wsqp);
    transpose2<<<dim3(48, 16, 2), 256, 0, stream>>>(w_attn, watT, wsqa, w_proj, wpT, wsqp);
    yat_gemm_qkv2<<<dim3(N1 / 128, ROWS / 128), 256, 0, stream>>>(
        xbf, watT, xsq, wsqa, b_attn, Qb, Kb, Vb, scale1);
    ropek_vtrans<<<dim3(TT / 64, BB * HH), 256, 0, stream>>>(
        (unsigned short*)Kb, (const unsigned short*)Vb, Vtb, rope);
    attn_mfma11<<<1024, 256, 0, stream>>>(Qb, Kb, Vtb, rope, aout, osq);
    yat_gemm_bk64<64, 64, float><<<dim3(CC / 64, ROWS / 64), 256, 0, stream>>>(
        aout, wpT, osq, wsqp, b_proj, out, ROWS, CC, CC, scale2);
}